// Round 13
// baseline (267.605 us; speedup 1.0000x reference)
//
#include <hip/hip_runtime.h>

typedef unsigned short u16;
typedef unsigned int u32;
typedef __attribute__((ext_vector_type(8))) short short8;
typedef __attribute__((ext_vector_type(4))) float f32x4;
typedef __attribute__((ext_vector_type(4))) u16 u16x4;
typedef __attribute__((ext_vector_type(2))) u32 uint2v;
typedef __attribute__((ext_vector_type(4))) u32 u32x4;

__device__ __forceinline__ u16 f2bf(float f) {
  union { float f; unsigned u; } x; x.f = f;
  unsigned r = (x.u + 0x7fffu + ((x.u >> 16) & 1u)) >> 16;
  return (u16)r;
}

__device__ __forceinline__ f32x4 mfma16(short8 a, short8 b, f32x4 c) {
  return __builtin_amdgcn_mfma_f32_16x16x32_bf16(a, b, c, 0, 0, 0);
}

__device__ __forceinline__ void gload16(const u16* g, u16* l) {
  __builtin_amdgcn_global_load_lds((const __attribute__((address_space(1))) void*)g,
                                   (__attribute__((address_space(3))) void*)l, 16, 0, 0);
}

// Fused prep: w_attn^T cast (0..1151), w_proj^T cast (1152..2175), x->bf16 (2176..4223).
__global__ __launch_bounds__(256) void prep(const float* __restrict__ x,
                                            const float* __restrict__ w_attn,
                                            const float* __restrict__ w_proj,
                                            u16* __restrict__ xb,
                                            u16* __restrict__ wat,
                                            u16* __restrict__ wpt) {
  __shared__ float tile[32][33];
  const int bid = blockIdx.x, tid = threadIdx.x;
  if (bid >= 2176) {
    const int id = bid - 2176;
    const f32x4* src = (const f32x4*)(x + (size_t)id * 4096);
    u16x4* dst = (u16x4*)(xb + (size_t)id * 4096);
#pragma unroll
    for (int c = 0; c < 4; ++c) {
      f32x4 v = src[c * 256 + tid];
      u16x4 o;
#pragma unroll
      for (int j = 0; j < 4; ++j) o[j] = f2bf(v[j]);
      dst[c * 256 + tid] = o;
    }
    return;
  }
  const float* src; u16* dst; int C, bx, by;
  if (bid < 1152) { src = w_attn; dst = wat; C = 1152; bx = bid % 36; by = bid / 36; }
  else { int id = bid - 1152; src = w_proj; dst = wpt; C = 1024; bx = id & 31; by = id >> 5; }
  const int R = 1024;
  const int tx = tid & 31, ty = tid >> 5;
  int c = bx * 32 + tx, r0 = by * 32;
#pragma unroll
  for (int i = 0; i < 32; i += 8)
    tile[ty + i][tx] = src[(size_t)(r0 + ty + i) * C + c];
  __syncthreads();
  int oc = r0 + tx, orow0 = bx * 32;
#pragma unroll
  for (int i = 0; i < 32; i += 8)
    dst[(size_t)(orow0 + ty + i) * R + oc] = f2bf(tile[tx][ty + i]);
}

// C[m][n] = sum_k A[m][k] * Bt[n][k].  128x128 tile, BK=32, 8 waves (512 thr).
// Round-21 DIAGNOSTIC v2: REP=true runs the K-loop FOUR times (tile index
// wraps, epilogue scales by 0.25f — exact power of two, bit-identical C).
// Round-20 (2x) gave the marginal-pass cost (+20.4us, L2-warm ~1530 cyc/step)
// but doubled-g1 still < 70.8us (absent from top-5) -> true g1 < 50us. 4x
// (g1 + ~61us = 86-111us) is GUARANTEED top-1: first-ever gemm counter row.
// Pre-committed reads: BANK_CONFLICT>=1e7 -> fragment-read conflicts (linear
// BK=32 layout) -> swizzle+ILP fix; Mfma<15 & VALU<40 & Occ~55 -> per-step
// serial lgkm/barrier chain -> ds_read->reg prefetch pipeline (untried);
// VALU>60 -> addressing; FETCH>=40MB -> L2 thrash -> XCD remap; Occ<30 ->
// co-residency broken.
template <bool C_F32, bool VT, bool REP>
__global__ __launch_bounds__(512) void gemm_bt(const u16* __restrict__ A,
                                               const u16* __restrict__ Bt,
                                               void* __restrict__ Cp,
                                               u16* __restrict__ vt,
                                               int lda, int ldb, int ldc, int K) {
  __shared__ u16 As[2][128 * 32];
  __shared__ u16 Bs[2][128 * 32];
  const int tid = threadIdx.x;
  const int wid = tid >> 6, lane = tid & 63;
  const int quad = lane >> 4, l15 = lane & 15;
  const int m0 = blockIdx.x * 128, n0 = blockIdx.y * 128;
  const int wm = (wid & 1) * 64;        // 2 wave-rows of 64
  const int wn = (wid >> 1) * 32;       // 4 wave-cols of 32
  const int sr = tid >> 2;              // 0..127 staging row
  const int sc = (tid & 3) * 8;         // staging col (x8 bf16 = 16B)

  f32x4 acc[4][2] = {};

  auto stage = [&](int t, int bb) {
    const int k0 = t << 5;
    gload16(A + (size_t)(m0 + sr) * lda + k0 + sc, &As[bb][wid * 512]);
    gload16(Bt + (size_t)(n0 + sr) * ldb + k0 + sc, &Bs[bb][wid * 512]);
  };

  const int nk = K >> 5;                       // power of two (K=1024 -> 32)
  const int total = REP ? (nk << 2) : nk;
  stage(0, 0);
  for (int t2 = 0; t2 < total; ++t2) {
    const int bb = t2 & 1;
    __syncthreads();
    if (t2 + 1 < total) stage((t2 + 1) & (nk - 1), bb ^ 1);
    short8 a[4], b[2];
#pragma unroll
    for (int i = 0; i < 4; ++i) a[i] = *(const short8*)&As[bb][(wm + 16 * i + l15) * 32 + quad * 8];
#pragma unroll
    for (int j = 0; j < 2; ++j) b[j] = *(const short8*)&Bs[bb][(wn + 16 * j + l15) * 32 + quad * 8];
#pragma unroll
    for (int i = 0; i < 4; ++i)
#pragma unroll
      for (int j = 0; j < 2; ++j)
        acc[i][j] = mfma16(a[i], b[j], acc[i][j]);
  }

  const float scale = REP ? 0.25f : 1.0f;
#pragma unroll
  for (int i = 0; i < 4; ++i) {
#pragma unroll
    for (int j = 0; j < 2; ++j) {
      const int mrow = m0 + wm + 16 * i + quad * 4;
      const int ncol = n0 + wn + 16 * j + l15;
#pragma unroll
      for (int r = 0; r < 4; ++r) {
        float v = acc[i][j][r] * scale;
        if (C_F32) {
          ((float*)Cp)[(size_t)(mrow + r) * ldc + ncol] = v;
        } else {
          u16 hv = f2bf(v);
          ((u16*)Cp)[(size_t)(mrow + r) * ldc + ncol] = hv;
          if (VT) {
            if (ncol >= 1088) {
              int mg = mrow + r;
              int bb2 = mg >> 11, tt = mg & 2047;
              vt[(size_t)(bb2 * 64 + (ncol - 1088)) * 2048 + tt] = hv;
            }
          }
        }
      }
    }
  }
}

// Flash causal MQA, S^T form, fixed-shift softmax, MFMA row-sum (ones trick),
// all-register permlane softmax redistribution, DMA K/V double-buffer with
// XOR granule swizzle. Round-14 config (69-71us). UNCHANGED.
__global__ __launch_bounds__(256) void attn_kernel(const u16* __restrict__ qkv,
                                                   const u16* __restrict__ vt,
                                                   u16* __restrict__ y) {
  const int T = 2048, LD = 1152;
  __shared__ u16 Ks[2][64 * 64];      // [buf][kv][d]   (XOR-swizzled granules)
  __shared__ u16 Vts[2][64 * 64];     // [buf][d][kv]   (XOR-swizzled granules)

  const int bid = blockIdx.x;
  const int qt = 15 - (bid >> 6);     // descending: long blocks launch first
  const int bh = bid & 63, b = bh >> 4, h = bh & 15;
  const int q0 = qt * 128;
  const int tid = threadIdx.x, wid = tid >> 6, lane = tid & 63;
  const int quad = lane >> 4, l15 = lane & 15;
  const int wq = wid * 32;
  const u16* qkvb = qkv + (size_t)b * T * LD;
  const u16* vtb = vt + (size_t)b * 64 * 2048;
  const int srow = lane >> 3;         // 0..7 within an 8-row DMA span
  const int sgx = (lane & 7) ^ srow;  // pre-swizzled source granule
  const float c1 = 0.18033688f;  // 0.125 * log2(e)
  const float M = 18.0f;         // fixed softmax shift
  short8 ones;
#pragma unroll
  for (int j = 0; j < 8; ++j) ones[j] = (short)0x3F80;  // bf16 1.0

  short8 qreg[2][2];
#pragma unroll
  for (int jt = 0; jt < 2; ++jt)
#pragma unroll
    for (int ks = 0; ks < 2; ++ks)
      qreg[jt][ks] = *(const short8*)(qkvb + (size_t)(q0 + wq + 16 * jt + l15) * LD + h * 64 + ks * 32 + quad * 8);

  f32x4 acc[4][2] = {};
  f32x4 accs[2] = {};   // row-sums via ones-MFMA

  auto stage = [&](int kv0n, int bb) {
#pragma unroll
    for (int c = 0; c < 2; ++c) {
      const int rb = wid * 16 + c * 8;      // rb % 8 == 0, so row&7 == srow
      const int row = rb + srow;
      gload16(qkvb + (size_t)(kv0n + row) * LD + 1024 + sgx * 8, &Ks[bb][rb * 64]);
      gload16(vtb + (size_t)row * 2048 + kv0n + sgx * 8, &Vts[bb][rb * 64]);
    }
  };

  const int ktmax = 2 * qt + 2;
  stage(0, 0);
  for (int kt = 0; kt < ktmax; ++kt) {
    const int kv0 = kt * 64;
    const int buf = kt & 1;
    __syncthreads();   // vmcnt(0)+lgkm drain: buf ready; prior reads of buf^1 done
    if (kt + 1 < ktmax) stage(kv0 + 64, buf ^ 1);
    if (kv0 > q0 + wq + 31) continue;  // fully masked for this wave

    // S^T = K * Q^T (kf shared across jt)
    f32x4 st[4][2] = {};
#pragma unroll
    for (int ks = 0; ks < 2; ++ks) {
      short8 kf[4];
#pragma unroll
      for (int i = 0; i < 4; ++i)
        kf[i] = *(const short8*)&Ks[buf][(16 * i + l15) * 64 + (((ks * 4 + quad) ^ (l15 & 7)) * 8)];
#pragma unroll
      for (int i = 0; i < 4; ++i)
#pragma unroll
        for (int jt = 0; jt < 2; ++jt)
          st[i][jt] = mfma16(kf[i], qreg[jt][ks], st[i][jt]);
    }

    // fixed-shift softmax -> pack -> all-register quad redistribution
    const bool needMask = (kv0 + 63 > q0 + wq);
    short8 pf[2][2];
#pragma unroll
    for (int jt = 0; jt < 2; ++jt) {
      const int qg = q0 + wq + 16 * jt + l15;
      u32 W[4][2];
#pragma unroll
      for (int i = 0; i < 4; ++i) {
        float p[4];
#pragma unroll
        for (int r = 0; r < 4; ++r) {
          p[r] = __builtin_amdgcn_exp2f(fmaf(st[i][jt][r], c1, -M));
          if (needMask && (kv0 + 16 * i + quad * 4 + r > qg)) p[r] = 0.f;
        }
        asm("v_cvt_pk_bf16_f32 %0, %1, %2" : "=v"(W[i][0]) : "v"(p[0]), "v"(p[1]));
        asm("v_cvt_pk_bf16_f32 %0, %1, %2" : "=v"(W[i][1]) : "v"(p[2]), "v"(p[3]));
      }
#pragma unroll
      for (int ks = 0; ks < 2; ++ks) {
        u32 P0, P1, P2, P3;
        {
          uint2v a = __builtin_amdgcn_permlane32_swap(W[2 * ks][0], W[2 * ks + 1][0], false, false);
          uint2v s = __builtin_amdgcn_permlane16_swap(a[0], a[1], false, false);
          P0 = s[0]; P2 = s[1];
        }
        {
          uint2v a = __builtin_amdgcn_permlane32_swap(W[2 * ks][1], W[2 * ks + 1][1], false, false);
          uint2v s = __builtin_amdgcn_permlane16_swap(a[0], a[1], false, false);
          P1 = s[0]; P3 = s[1];
        }
        union { u32x4 u; short8 s; } cv;
        cv.u = (u32x4){P0, P1, P2, P3};
        pf[jt][ks] = cv.s;
      }
    }

    // O^T += V^T * P^T ; row-sum += ones * P^T (Vts frags shared across jt)
#pragma unroll
    for (int ks = 0; ks < 2; ++ks) {
#pragma unroll
      for (int id = 0; id < 4; ++id) {
        short8 vf = *(const short8*)&Vts[buf][(16 * id + l15) * 64 + (((ks * 4 + quad) ^ (l15 & 7)) * 8)];
        acc[id][0] = mfma16(vf, pf[0][ks], acc[id][0]);
        acc[id][1] = mfma16(vf, pf[1][ks], acc[id][1]);
      }
      accs[0] = mfma16(ones, pf[0][ks], accs[0]);
      accs[1] = mfma16(ones, pf[1][ks], accs[1]);
    }
  }

  // epilogue: every element of accs[jt] equals this q-col's row-sum
#pragma unroll
  for (int jt = 0; jt < 2; ++jt) {
    const float inv = 1.f / accs[jt][0];
    const int qg = q0 + wq + 16 * jt + l15;
#pragma unroll
    for (int id = 0; id < 4; ++id) {
      u16x4 o;
#pragma unroll
      for (int r = 0; r < 4; ++r) o[r] = f2bf(acc[id][jt][r] * inv);
      *(u16x4*)(y + (size_t)(b * T + qg) * 1024 + h * 64 + 16 * id + quad * 4) = o;
    }
  }
}

extern "C" void kernel_launch(void* const* d_in, const int* in_sizes, int n_in,
                              void* d_out, int out_size, void* d_ws, size_t ws_size,
                              hipStream_t stream) {
  const float* x = (const float*)d_in[0];       // (4,2048,1024)
  const float* w_attn = (const float*)d_in[1];  // (1024,1152)
  const float* w_proj = (const float*)d_in[2];  // (1024,1024)
  float* out = (float*)d_out;                   // (4,2048,1024) fp32
  char* ws = (char*)d_ws;

  u16* wat = (u16*)ws;                       // 1152x1024 bf16
  u16* wpt = (u16*)(ws + 2359296);           // 1024x1024 bf16
  u16* xb  = (u16*)(ws + 4456448);           // 8192x1024 bf16
  u16* qkv = (u16*)(ws + 21233664);          // 8192x1152 bf16
  u16* vt  = (u16*)(ws + 40108032);          // 4x64x2048 bf16
  u16* y   = (u16*)(ws + 41156608);          // 8192x1024 bf16

  prep<<<dim3(4224), dim3(256), 0, stream>>>(x, w_attn, w_proj, xb, wat, wpt);
  gemm_bt<false, true, true><<<dim3(64, 9), dim3(512), 0, stream>>>(xb, wat, qkv, vt, 1024, 1024, 1152, 1024);
  attn_kernel<<<dim3(1024), dim3(256), 0, stream>>>(qkv, vt, y);
  gemm_bt<true, false, false><<<dim3(64, 8), dim3(512), 0, stream>>>(y, wpt, out, nullptr, 1024, 1024, 1024, 1024);
}

// Round 14
// 245.363 us; speedup vs baseline: 1.0906x; 1.0906x over previous
//
#include <hip/hip_runtime.h>

typedef unsigned short u16;
typedef unsigned int u32;
typedef __attribute__((ext_vector_type(8))) short short8;
typedef __attribute__((ext_vector_type(4))) float f32x4;
typedef __attribute__((ext_vector_type(4))) u16 u16x4;
typedef __attribute__((ext_vector_type(2))) u32 uint2v;
typedef __attribute__((ext_vector_type(4))) u32 u32x4;

__device__ __forceinline__ u16 f2bf(float f) {
  union { float f; unsigned u; } x; x.f = f;
  unsigned r = (x.u + 0x7fffu + ((x.u >> 16) & 1u)) >> 16;
  return (u16)r;
}

__device__ __forceinline__ f32x4 mfma16(short8 a, short8 b, f32x4 c) {
  return __builtin_amdgcn_mfma_f32_16x16x32_bf16(a, b, c, 0, 0, 0);
}

__device__ __forceinline__ void gload16(const u16* g, u16* l) {
  __builtin_amdgcn_global_load_lds((const __attribute__((address_space(1))) void*)g,
                                   (__attribute__((address_space(3))) void*)l, 16, 0, 0);
}

// Fused prep: w_attn^T cast (0..1151), w_proj^T cast (1152..2175), x->bf16 (2176..4223).
__global__ __launch_bounds__(256) void prep(const float* __restrict__ x,
                                            const float* __restrict__ w_attn,
                                            const float* __restrict__ w_proj,
                                            u16* __restrict__ xb,
                                            u16* __restrict__ wat,
                                            u16* __restrict__ wpt) {
  __shared__ float tile[32][33];
  const int bid = blockIdx.x, tid = threadIdx.x;
  if (bid >= 2176) {
    const int id = bid - 2176;
    const f32x4* src = (const f32x4*)(x + (size_t)id * 4096);
    u16x4* dst = (u16x4*)(xb + (size_t)id * 4096);
#pragma unroll
    for (int c = 0; c < 4; ++c) {
      f32x4 v = src[c * 256 + tid];
      u16x4 o;
#pragma unroll
      for (int j = 0; j < 4; ++j) o[j] = f2bf(v[j]);
      dst[c * 256 + tid] = o;
    }
    return;
  }
  const float* src; u16* dst; int C, bx, by;
  if (bid < 1152) { src = w_attn; dst = wat; C = 1152; bx = bid % 36; by = bid / 36; }
  else { int id = bid - 1152; src = w_proj; dst = wpt; C = 1024; bx = id & 31; by = id >> 5; }
  const int R = 1024;
  const int tx = tid & 31, ty = tid >> 5;
  int c = bx * 32 + tx, r0 = by * 32;
#pragma unroll
  for (int i = 0; i < 32; i += 8)
    tile[ty + i][tx] = src[(size_t)(r0 + ty + i) * C + c];
  __syncthreads();
  int oc = r0 + tx, orow0 = bx * 32;
#pragma unroll
  for (int i = 0; i < 32; i += 8)
    dst[(size_t)(orow0 + ty + i) * R + oc] = f2bf(tile[tx][ty + i]);
}

// C[m][n] = sum_k A[m][k] * Bt[n][k].  128x128 tile, BK=32, 8 waves (512 thr).
// Round-22: B REMOVED FROM LDS — loaded per-step global->register.
// Round-21's first-ever gemm counters: warm step = 1530 cyc/CU vs LDS-pipe
// model 1584 (18 waves x 6 ds_read_b128 x 12cyc + 288 DMA-write) -> the warm
// K-loop is LDS-BW-saturated, which explains rounds 7-10 all being flat (none
// cut LDS bytes). B is L2-resident (2.3/2.1 MB): each wave loads b[2] direct
// from global — per (j,l15) row the 4 quads read one contiguous 64B line.
// Removes 2 of 6 ds_reads + 1 of 2 DMAs per wave-step: LDS pipe ~1584->1010.
// ORDER: b-loads issue BEFORE stage(t+1)'s DMA so the compiler's wait for b
// is vmcnt(1) (prefetch DMA stays in flight); issuing b after the DMA would
// force vmcnt(0) at b-use and serialize the prefetch into the compute phase.
template <bool C_F32, bool VT>
__global__ __launch_bounds__(512) void gemm_bt(const u16* __restrict__ A,
                                               const u16* __restrict__ Bt,
                                               void* __restrict__ Cp,
                                               u16* __restrict__ vt,
                                               int lda, int ldb, int ldc, int K) {
  __shared__ u16 As[2][128 * 32];
  const int tid = threadIdx.x;
  const int wid = tid >> 6, lane = tid & 63;
  const int quad = lane >> 4, l15 = lane & 15;
  const int m0 = blockIdx.x * 128, n0 = blockIdx.y * 128;
  const int wm = (wid & 1) * 64;        // 2 wave-rows of 64
  const int wn = (wid >> 1) * 32;       // 4 wave-cols of 32
  const int sr = tid >> 2;              // 0..127 staging row
  const int sc = (tid & 3) * 8;         // staging col (x8 bf16 = 16B)

  f32x4 acc[4][2] = {};

  auto stageA = [&](int t, int bb) {
    const int k0 = t << 5;
    gload16(A + (size_t)(m0 + sr) * lda + k0 + sc, &As[bb][wid * 512]);
  };

  const u16* brow0 = Bt + (size_t)(n0 + wn + l15) * ldb + quad * 8;
  const u16* brow1 = brow0 + (size_t)16 * ldb;

  const int nk = K >> 5;
  stageA(0, 0);
  for (int t = 0; t < nk; ++t) {
    const int bb = t & 1;
    const int k0 = t << 5;
    __syncthreads();
    // b first (older in vmcnt order), then the prefetch DMA
    short8 b[2];
    b[0] = *(const short8*)(brow0 + k0);
    b[1] = *(const short8*)(brow1 + k0);
    if (t + 1 < nk) stageA(t + 1, bb ^ 1);
    short8 a[4];
#pragma unroll
    for (int i = 0; i < 4; ++i) a[i] = *(const short8*)&As[bb][(wm + 16 * i + l15) * 32 + quad * 8];
#pragma unroll
    for (int i = 0; i < 4; ++i)
#pragma unroll
      for (int j = 0; j < 2; ++j)
        acc[i][j] = mfma16(a[i], b[j], acc[i][j]);
  }

#pragma unroll
  for (int i = 0; i < 4; ++i) {
#pragma unroll
    for (int j = 0; j < 2; ++j) {
      const int mrow = m0 + wm + 16 * i + quad * 4;
      const int ncol = n0 + wn + 16 * j + l15;
#pragma unroll
      for (int r = 0; r < 4; ++r) {
        float v = acc[i][j][r];
        if (C_F32) {
          ((float*)Cp)[(size_t)(mrow + r) * ldc + ncol] = v;
        } else {
          u16 hv = f2bf(v);
          ((u16*)Cp)[(size_t)(mrow + r) * ldc + ncol] = hv;
          if (VT) {
            if (ncol >= 1088) {
              int mg = mrow + r;
              int bb2 = mg >> 11, tt = mg & 2047;
              vt[(size_t)(bb2 * 64 + (ncol - 1088)) * 2048 + tt] = hv;
            }
          }
        }
      }
    }
  }
}

// Flash causal MQA, S^T form, fixed-shift softmax, MFMA row-sum (ones trick),
// all-register permlane softmax redistribution, DMA K/V double-buffer with
// XOR granule swizzle. Round-14 config (69-71us). UNCHANGED.
__global__ __launch_bounds__(256) void attn_kernel(const u16* __restrict__ qkv,
                                                   const u16* __restrict__ vt,
                                                   u16* __restrict__ y) {
  const int T = 2048, LD = 1152;
  __shared__ u16 Ks[2][64 * 64];      // [buf][kv][d]   (XOR-swizzled granules)
  __shared__ u16 Vts[2][64 * 64];     // [buf][d][kv]   (XOR-swizzled granules)

  const int bid = blockIdx.x;
  const int qt = 15 - (bid >> 6);     // descending: long blocks launch first
  const int bh = bid & 63, b = bh >> 4, h = bh & 15;
  const int q0 = qt * 128;
  const int tid = threadIdx.x, wid = tid >> 6, lane = tid & 63;
  const int quad = lane >> 4, l15 = lane & 15;
  const int wq = wid * 32;
  const u16* qkvb = qkv + (size_t)b * T * LD;
  const u16* vtb = vt + (size_t)b * 64 * 2048;
  const int srow = lane >> 3;         // 0..7 within an 8-row DMA span
  const int sgx = (lane & 7) ^ srow;  // pre-swizzled source granule
  const float c1 = 0.18033688f;  // 0.125 * log2(e)
  const float M = 18.0f;         // fixed softmax shift
  short8 ones;
#pragma unroll
  for (int j = 0; j < 8; ++j) ones[j] = (short)0x3F80;  // bf16 1.0

  short8 qreg[2][2];
#pragma unroll
  for (int jt = 0; jt < 2; ++jt)
#pragma unroll
    for (int ks = 0; ks < 2; ++ks)
      qreg[jt][ks] = *(const short8*)(qkvb + (size_t)(q0 + wq + 16 * jt + l15) * LD + h * 64 + ks * 32 + quad * 8);

  f32x4 acc[4][2] = {};
  f32x4 accs[2] = {};   // row-sums via ones-MFMA

  auto stage = [&](int kv0n, int bb) {
#pragma unroll
    for (int c = 0; c < 2; ++c) {
      const int rb = wid * 16 + c * 8;      // rb % 8 == 0, so row&7 == srow
      const int row = rb + srow;
      gload16(qkvb + (size_t)(kv0n + row) * LD + 1024 + sgx * 8, &Ks[bb][rb * 64]);
      gload16(vtb + (size_t)row * 2048 + kv0n + sgx * 8, &Vts[bb][rb * 64]);
    }
  };

  const int ktmax = 2 * qt + 2;
  stage(0, 0);
  for (int kt = 0; kt < ktmax; ++kt) {
    const int kv0 = kt * 64;
    const int buf = kt & 1;
    __syncthreads();   // vmcnt(0)+lgkm drain: buf ready; prior reads of buf^1 done
    if (kt + 1 < ktmax) stage(kv0 + 64, buf ^ 1);
    if (kv0 > q0 + wq + 31) continue;  // fully masked for this wave

    // S^T = K * Q^T (kf shared across jt)
    f32x4 st[4][2] = {};
#pragma unroll
    for (int ks = 0; ks < 2; ++ks) {
      short8 kf[4];
#pragma unroll
      for (int i = 0; i < 4; ++i)
        kf[i] = *(const short8*)&Ks[buf][(16 * i + l15) * 64 + (((ks * 4 + quad) ^ (l15 & 7)) * 8)];
#pragma unroll
      for (int i = 0; i < 4; ++i)
#pragma unroll
        for (int jt = 0; jt < 2; ++jt)
          st[i][jt] = mfma16(kf[i], qreg[jt][ks], st[i][jt]);
    }

    // fixed-shift softmax -> pack -> all-register quad redistribution
    const bool needMask = (kv0 + 63 > q0 + wq);
    short8 pf[2][2];
#pragma unroll
    for (int jt = 0; jt < 2; ++jt) {
      const int qg = q0 + wq + 16 * jt + l15;
      u32 W[4][2];
#pragma unroll
      for (int i = 0; i < 4; ++i) {
        float p[4];
#pragma unroll
        for (int r = 0; r < 4; ++r) {
          p[r] = __builtin_amdgcn_exp2f(fmaf(st[i][jt][r], c1, -M));
          if (needMask && (kv0 + 16 * i + quad * 4 + r > qg)) p[r] = 0.f;
        }
        asm("v_cvt_pk_bf16_f32 %0, %1, %2" : "=v"(W[i][0]) : "v"(p[0]), "v"(p[1]));
        asm("v_cvt_pk_bf16_f32 %0, %1, %2" : "=v"(W[i][1]) : "v"(p[2]), "v"(p[3]));
      }
#pragma unroll
      for (int ks = 0; ks < 2; ++ks) {
        u32 P0, P1, P2, P3;
        {
          uint2v a = __builtin_amdgcn_permlane32_swap(W[2 * ks][0], W[2 * ks + 1][0], false, false);
          uint2v s = __builtin_amdgcn_permlane16_swap(a[0], a[1], false, false);
          P0 = s[0]; P2 = s[1];
        }
        {
          uint2v a = __builtin_amdgcn_permlane32_swap(W[2 * ks][1], W[2 * ks + 1][1], false, false);
          uint2v s = __builtin_amdgcn_permlane16_swap(a[0], a[1], false, false);
          P1 = s[0]; P3 = s[1];
        }
        union { u32x4 u; short8 s; } cv;
        cv.u = (u32x4){P0, P1, P2, P3};
        pf[jt][ks] = cv.s;
      }
    }

    // O^T += V^T * P^T ; row-sum += ones * P^T (Vts frags shared across jt)
#pragma unroll
    for (int ks = 0; ks < 2; ++ks) {
#pragma unroll
      for (int id = 0; id < 4; ++id) {
        short8 vf = *(const short8*)&Vts[buf][(16 * id + l15) * 64 + (((ks * 4 + quad) ^ (l15 & 7)) * 8)];
        acc[id][0] = mfma16(vf, pf[0][ks], acc[id][0]);
        acc[id][1] = mfma16(vf, pf[1][ks], acc[id][1]);
      }
      accs[0] = mfma16(ones, pf[0][ks], accs[0]);
      accs[1] = mfma16(ones, pf[1][ks], accs[1]);
    }
  }

  // epilogue: every element of accs[jt] equals this q-col's row-sum
#pragma unroll
  for (int jt = 0; jt < 2; ++jt) {
    const float inv = 1.f / accs[jt][0];
    const int qg = q0 + wq + 16 * jt + l15;
#pragma unroll
    for (int id = 0; id < 4; ++id) {
      u16x4 o;
#pragma unroll
      for (int r = 0; r < 4; ++r) o[r] = f2bf(acc[id][jt][r] * inv);
      *(u16x4*)(y + (size_t)(b * T + qg) * 1024 + h * 64 + 16 * id + quad * 4) = o;
    }
  }
}

extern "C" void kernel_launch(void* const* d_in, const int* in_sizes, int n_in,
                              void* d_out, int out_size, void* d_ws, size_t ws_size,
                              hipStream_t stream) {
  const float* x = (const float*)d_in[0];       // (4,2048,1024)
  const float* w_attn = (const float*)d_in[1];  // (1024,1152)
  const float* w_proj = (const float*)d_in[2];  // (1024,1024)
  float* out = (float*)d_out;                   // (4,2048,1024) fp32
  char* ws = (char*)d_ws;

  u16* wat = (u16*)ws;                       // 1152x1024 bf16
  u16* wpt = (u16*)(ws + 2359296);           // 1024x1024 bf16
  u16* xb  = (u16*)(ws + 4456448);           // 8192x1024 bf16
  u16* qkv = (u16*)(ws + 21233664);          // 8192x1152 bf16
  u16* vt  = (u16*)(ws + 40108032);          // 4x64x2048 bf16
  u16* y   = (u16*)(ws + 41156608);          // 8192x1024 bf16

  prep<<<dim3(4224), dim3(256), 0, stream>>>(x, w_attn, w_proj, xb, wat, wpt);
  gemm_bt<false, true><<<dim3(64, 9), dim3(512), 0, stream>>>(xb, wat, qkv, vt, 1024, 1024, 1152, 1024);
  attn_kernel<<<dim3(1024), dim3(256), 0, stream>>>(qkv, vt, y);
  gemm_bt<true, false><<<dim3(64, 8), dim3(512), 0, stream>>>(y, wpt, out, nullptr, 1024, 1024, 1024, 1024);
}

// Round 15
// 202.075 us; speedup vs baseline: 1.3243x; 1.2142x over previous
//
#include <hip/hip_runtime.h>

typedef unsigned short u16;
typedef unsigned int u32;
typedef __attribute__((ext_vector_type(8))) short short8;
typedef __attribute__((ext_vector_type(4))) float f32x4;
typedef __attribute__((ext_vector_type(4))) u16 u16x4;
typedef __attribute__((ext_vector_type(2))) u32 uint2v;
typedef __attribute__((ext_vector_type(4))) u32 u32x4;

__device__ __forceinline__ u16 f2bf(float f) {
  union { float f; unsigned u; } x; x.f = f;
  unsigned r = (x.u + 0x7fffu + ((x.u >> 16) & 1u)) >> 16;
  return (u16)r;
}

__device__ __forceinline__ f32x4 mfma16(short8 a, short8 b, f32x4 c) {
  return __builtin_amdgcn_mfma_f32_16x16x32_bf16(a, b, c, 0, 0, 0);
}

__device__ __forceinline__ void gload16(const u16* g, u16* l) {
  __builtin_amdgcn_global_load_lds((const __attribute__((address_space(1))) void*)g,
                                   (__attribute__((address_space(3))) void*)l, 16, 0, 0);
}

// Fused prep: w_attn^T cast (0..1151), w_proj^T cast (1152..2175), x->bf16 (2176..4223).
__global__ __launch_bounds__(256) void prep(const float* __restrict__ x,
                                            const float* __restrict__ w_attn,
                                            const float* __restrict__ w_proj,
                                            u16* __restrict__ xb,
                                            u16* __restrict__ wat,
                                            u16* __restrict__ wpt) {
  __shared__ float tile[32][33];
  const int bid = blockIdx.x, tid = threadIdx.x;
  if (bid >= 2176) {
    const int id = bid - 2176;
    const f32x4* src = (const f32x4*)(x + (size_t)id * 4096);
    u16x4* dst = (u16x4*)(xb + (size_t)id * 4096);
#pragma unroll
    for (int c = 0; c < 4; ++c) {
      f32x4 v = src[c * 256 + tid];
      u16x4 o;
#pragma unroll
      for (int j = 0; j < 4; ++j) o[j] = f2bf(v[j]);
      dst[c * 256 + tid] = o;
    }
    return;
  }
  const float* src; u16* dst; int C, bx, by;
  if (bid < 1152) { src = w_attn; dst = wat; C = 1152; bx = bid % 36; by = bid / 36; }
  else { int id = bid - 1152; src = w_proj; dst = wpt; C = 1024; bx = id & 31; by = id >> 5; }
  const int R = 1024;
  const int tx = tid & 31, ty = tid >> 5;
  int c = bx * 32 + tx, r0 = by * 32;
#pragma unroll
  for (int i = 0; i < 32; i += 8)
    tile[ty + i][tx] = src[(size_t)(r0 + ty + i) * C + c];
  __syncthreads();
  int oc = r0 + tx, orow0 = bx * 32;
#pragma unroll
  for (int i = 0; i < 32; i += 8)
    dst[(size_t)(orow0 + ty + i) * R + oc] = f2bf(tile[tx][ty + i]);
}

// C[m][n] = sum_k A[m][k] * Bt[n][k].  128x128 tile, BK=32, 8 waves (512 thr).
// Round-23: round-15 base (best total 202.7us) + XOR granule swizzle on the
// GEMM LDS — the fix round-21's counter row directly indicated:
// SQ_LDS_BANK_CONFLICT=1.4e7 on gemm (~21% of gemm cycles/CU in conflict
// stalls; attn's swizzled tiles measure 0). Linear BK=32 has 64B rows: l15
// lanes at stride 64B hit 2 of 8 granule classes -> 8-way ds_read conflicts.
// Row-pair layout (64 row-pairs x 128B): position (rp,g') holds granule
// g = g'^(rp&7). DMA stays LINEAR (dest = wavebase + lane*16B); per-lane
// GLOBAL source pre-swizzled: sg=(lane&7)^(lane>>3), reads row
// wid*16+2*(lane>>3)+(sg>>2), k-granule sg&3. Read side:
// g' = (((l15&1)<<2)|quad) ^ (l15>>1) -> all 8 classes x2 lanes = b128 floor,
// 0 conflicts. Round-22's global-B regression (+40us) reverted: per-wave
// scattered L2 loads in the lockstep compute phase cost more than ds_reads.
template <bool C_F32, bool VT>
__global__ __launch_bounds__(512) void gemm_bt(const u16* __restrict__ A,
                                               const u16* __restrict__ Bt,
                                               void* __restrict__ Cp,
                                               u16* __restrict__ vt,
                                               int lda, int ldb, int ldc, int K) {
  __shared__ u16 As[2][128 * 32];
  __shared__ u16 Bs[2][128 * 32];
  const int tid = threadIdx.x;
  const int wid = tid >> 6, lane = tid & 63;
  const int quad = lane >> 4, l15 = lane & 15;
  const int m0 = blockIdx.x * 128, n0 = blockIdx.y * 128;
  const int wm = (wid & 1) * 64;        // 2 wave-rows of 64
  const int wn = (wid >> 1) * 32;       // 4 wave-cols of 32
  // staging source pre-swizzle (content for linear LDS position = lane)
  const int srp = lane >> 3;            // row-pair within wave's 8 (0..7)
  const int sg = (lane & 7) ^ srp;      // content granule for this position
  const int srow = wid * 16 + 2 * srp + (sg >> 2);  // real row in tile
  const int skc = (sg & 3) * 8;         // k-offset (u16)
  // fragment-read swizzled granule
  const int rhalf = l15 >> 1;
  const int gread = ((((l15 & 1) << 2) | quad) ^ rhalf) * 8;
  const int roff = rhalf * 64 + gread;  // offset within 16-row span (u16)

  f32x4 acc[4][2] = {};

  auto stage = [&](int t, int bb) {
    const int k0 = t << 5;
    gload16(A + (size_t)(m0 + srow) * lda + k0 + skc, &As[bb][wid * 512]);
    gload16(Bt + (size_t)(n0 + srow) * ldb + k0 + skc, &Bs[bb][wid * 512]);
  };

  const int nk = K >> 5;
  stage(0, 0);
  for (int t = 0; t < nk; ++t) {
    const int bb = t & 1;
    __syncthreads();
    if (t + 1 < nk) stage(t + 1, bb ^ 1);
    short8 a[4], b[2];
#pragma unroll
    for (int i = 0; i < 4; ++i) a[i] = *(const short8*)&As[bb][(wm + 16 * i) * 32 + roff];
#pragma unroll
    for (int j = 0; j < 2; ++j) b[j] = *(const short8*)&Bs[bb][(wn + 16 * j) * 32 + roff];
#pragma unroll
    for (int i = 0; i < 4; ++i)
#pragma unroll
      for (int j = 0; j < 2; ++j)
        acc[i][j] = mfma16(a[i], b[j], acc[i][j]);
  }

#pragma unroll
  for (int i = 0; i < 4; ++i) {
#pragma unroll
    for (int j = 0; j < 2; ++j) {
      const int mrow = m0 + wm + 16 * i + quad * 4;
      const int ncol = n0 + wn + 16 * j + l15;
#pragma unroll
      for (int r = 0; r < 4; ++r) {
        float v = acc[i][j][r];
        if (C_F32) {
          ((float*)Cp)[(size_t)(mrow + r) * ldc + ncol] = v;
        } else {
          u16 hv = f2bf(v);
          ((u16*)Cp)[(size_t)(mrow + r) * ldc + ncol] = hv;
          if (VT) {
            if (ncol >= 1088) {
              int mg = mrow + r;
              int bb2 = mg >> 11, tt = mg & 2047;
              vt[(size_t)(bb2 * 64 + (ncol - 1088)) * 2048 + tt] = hv;
            }
          }
        }
      }
    }
  }
}

// Flash causal MQA, S^T form, fixed-shift softmax, MFMA row-sum (ones trick),
// all-register permlane softmax redistribution, DMA K/V double-buffer with
// XOR granule swizzle. Round-14 config (69-71us). UNCHANGED.
__global__ __launch_bounds__(256) void attn_kernel(const u16* __restrict__ qkv,
                                                   const u16* __restrict__ vt,
                                                   u16* __restrict__ y) {
  const int T = 2048, LD = 1152;
  __shared__ u16 Ks[2][64 * 64];      // [buf][kv][d]   (XOR-swizzled granules)
  __shared__ u16 Vts[2][64 * 64];     // [buf][d][kv]   (XOR-swizzled granules)

  const int bid = blockIdx.x;
  const int qt = 15 - (bid >> 6);     // descending: long blocks launch first
  const int bh = bid & 63, b = bh >> 4, h = bh & 15;
  const int q0 = qt * 128;
  const int tid = threadIdx.x, wid = tid >> 6, lane = tid & 63;
  const int quad = lane >> 4, l15 = lane & 15;
  const int wq = wid * 32;
  const u16* qkvb = qkv + (size_t)b * T * LD;
  const u16* vtb = vt + (size_t)b * 64 * 2048;
  const int srow = lane >> 3;         // 0..7 within an 8-row DMA span
  const int sgx = (lane & 7) ^ srow;  // pre-swizzled source granule
  const float c1 = 0.18033688f;  // 0.125 * log2(e)
  const float M = 18.0f;         // fixed softmax shift
  short8 ones;
#pragma unroll
  for (int j = 0; j < 8; ++j) ones[j] = (short)0x3F80;  // bf16 1.0

  short8 qreg[2][2];
#pragma unroll
  for (int jt = 0; jt < 2; ++jt)
#pragma unroll
    for (int ks = 0; ks < 2; ++ks)
      qreg[jt][ks] = *(const short8*)(qkvb + (size_t)(q0 + wq + 16 * jt + l15) * LD + h * 64 + ks * 32 + quad * 8);

  f32x4 acc[4][2] = {};
  f32x4 accs[2] = {};   // row-sums via ones-MFMA

  auto stage = [&](int kv0n, int bb) {
#pragma unroll
    for (int c = 0; c < 2; ++c) {
      const int rb = wid * 16 + c * 8;      // rb % 8 == 0, so row&7 == srow
      const int row = rb + srow;
      gload16(qkvb + (size_t)(kv0n + row) * LD + 1024 + sgx * 8, &Ks[bb][rb * 64]);
      gload16(vtb + (size_t)row * 2048 + kv0n + sgx * 8, &Vts[bb][rb * 64]);
    }
  };

  const int ktmax = 2 * qt + 2;
  stage(0, 0);
  for (int kt = 0; kt < ktmax; ++kt) {
    const int kv0 = kt * 64;
    const int buf = kt & 1;
    __syncthreads();   // vmcnt(0)+lgkm drain: buf ready; prior reads of buf^1 done
    if (kt + 1 < ktmax) stage(kv0 + 64, buf ^ 1);
    if (kv0 > q0 + wq + 31) continue;  // fully masked for this wave

    // S^T = K * Q^T (kf shared across jt)
    f32x4 st[4][2] = {};
#pragma unroll
    for (int ks = 0; ks < 2; ++ks) {
      short8 kf[4];
#pragma unroll
      for (int i = 0; i < 4; ++i)
        kf[i] = *(const short8*)&Ks[buf][(16 * i + l15) * 64 + (((ks * 4 + quad) ^ (l15 & 7)) * 8)];
#pragma unroll
      for (int i = 0; i < 4; ++i)
#pragma unroll
        for (int jt = 0; jt < 2; ++jt)
          st[i][jt] = mfma16(kf[i], qreg[jt][ks], st[i][jt]);
    }

    // fixed-shift softmax -> pack -> all-register quad redistribution
    const bool needMask = (kv0 + 63 > q0 + wq);
    short8 pf[2][2];
#pragma unroll
    for (int jt = 0; jt < 2; ++jt) {
      const int qg = q0 + wq + 16 * jt + l15;
      u32 W[4][2];
#pragma unroll
      for (int i = 0; i < 4; ++i) {
        float p[4];
#pragma unroll
        for (int r = 0; r < 4; ++r) {
          p[r] = __builtin_amdgcn_exp2f(fmaf(st[i][jt][r], c1, -M));
          if (needMask && (kv0 + 16 * i + quad * 4 + r > qg)) p[r] = 0.f;
        }
        asm("v_cvt_pk_bf16_f32 %0, %1, %2" : "=v"(W[i][0]) : "v"(p[0]), "v"(p[1]));
        asm("v_cvt_pk_bf16_f32 %0, %1, %2" : "=v"(W[i][1]) : "v"(p[2]), "v"(p[3]));
      }
#pragma unroll
      for (int ks = 0; ks < 2; ++ks) {
        u32 P0, P1, P2, P3;
        {
          uint2v a = __builtin_amdgcn_permlane32_swap(W[2 * ks][0], W[2 * ks + 1][0], false, false);
          uint2v s = __builtin_amdgcn_permlane16_swap(a[0], a[1], false, false);
          P0 = s[0]; P2 = s[1];
        }
        {
          uint2v a = __builtin_amdgcn_permlane32_swap(W[2 * ks][1], W[2 * ks + 1][1], false, false);
          uint2v s = __builtin_amdgcn_permlane16_swap(a[0], a[1], false, false);
          P1 = s[0]; P3 = s[1];
        }
        union { u32x4 u; short8 s; } cv;
        cv.u = (u32x4){P0, P1, P2, P3};
        pf[jt][ks] = cv.s;
      }
    }

    // O^T += V^T * P^T ; row-sum += ones * P^T (Vts frags shared across jt)
#pragma unroll
    for (int ks = 0; ks < 2; ++ks) {
#pragma unroll
      for (int id = 0; id < 4; ++id) {
        short8 vf = *(const short8*)&Vts[buf][(16 * id + l15) * 64 + (((ks * 4 + quad) ^ (l15 & 7)) * 8)];
        acc[id][0] = mfma16(vf, pf[0][ks], acc[id][0]);
        acc[id][1] = mfma16(vf, pf[1][ks], acc[id][1]);
      }
      accs[0] = mfma16(ones, pf[0][ks], accs[0]);
      accs[1] = mfma16(ones, pf[1][ks], accs[1]);
    }
  }

  // epilogue: every element of accs[jt] equals this q-col's row-sum
#pragma unroll
  for (int jt = 0; jt < 2; ++jt) {
    const float inv = 1.f / accs[jt][0];
    const int qg = q0 + wq + 16 * jt + l15;
#pragma unroll
    for (int id = 0; id < 4; ++id) {
      u16x4 o;
#pragma unroll
      for (int r = 0; r < 4; ++r) o[r] = f2bf(acc[id][jt][r] * inv);
      *(u16x4*)(y + (size_t)(b * T + qg) * 1024 + h * 64 + 16 * id + quad * 4) = o;
    }
  }
}

extern "C" void kernel_launch(void* const* d_in, const int* in_sizes, int n_in,
                              void* d_out, int out_size, void* d_ws, size_t ws_size,
                              hipStream_t stream) {
  const float* x = (const float*)d_in[0];       // (4,2048,1024)
  const float* w_attn = (const float*)d_in[1];  // (1024,1152)
  const float* w_proj = (const float*)d_in[2];  // (1024,1024)
  float* out = (float*)d_out;                   // (4,2048,1024) fp32
  char* ws = (char*)d_ws;

  u16* wat = (u16*)ws;                       // 1152x1024 bf16
  u16* wpt = (u16*)(ws + 2359296);           // 1024x1024 bf16
  u16* xb  = (u16*)(ws + 4456448);           // 8192x1024 bf16
  u16* qkv = (u16*)(ws + 21233664);          // 8192x1152 bf16
  u16* vt  = (u16*)(ws + 40108032);          // 4x64x2048 bf16
  u16* y   = (u16*)(ws + 41156608);          // 8192x1024 bf16

  prep<<<dim3(4224), dim3(256), 0, stream>>>(x, w_attn, w_proj, xb, wat, wpt);
  gemm_bt<false, true><<<dim3(64, 9), dim3(512), 0, stream>>>(xb, wat, qkv, vt, 1024, 1024, 1152, 1024);
  attn_kernel<<<dim3(1024), dim3(256), 0, stream>>>(qkv, vt, y);
  gemm_bt<true, false><<<dim3(64, 8), dim3(512), 0, stream>>>(y, wpt, out, nullptr, 1024, 1024, 1024, 1024);
}